// Round 1
// baseline (1021.175 us; speedup 1.0000x reference)
//
#include <hip/hip_runtime.h>
#include <hip/hip_bf16.h>
#include <stdint.h>

typedef __bf16 bf16x8 __attribute__((ext_vector_type(8)));
typedef float f32x4 __attribute__((ext_vector_type(4)));
typedef unsigned short u16;

typedef __attribute__((address_space(1))) void as1_void;
typedef __attribute__((address_space(3))) void as3_void;

__device__ __forceinline__ u16 f2bf(float f) {
  uint32_t u = __float_as_uint(f);
  u += 0x7fffu + ((u >> 16) & 1u);
  return (u16)(u >> 16);
}

// ---------------- fp32 -> bf16 convert (weights) ----------------
__global__ __launch_bounds__(256) void cvt_kernel(const float4* __restrict__ in,
                                                  ushort4* __restrict__ out, int n4) {
  int i = blockIdx.x * 256 + threadIdx.x;
  if (i < n4) {
    float4 v = in[i];
    ushort4 o;
    o.x = f2bf(v.x); o.y = f2bf(v.y); o.z = f2bf(v.z); o.w = f2bf(v.w);
    out[i] = o;
  }
}

// ---------------- layernorm fp32 -> bf16, D=1024 ----------------
__global__ __launch_bounds__(256) void ln_kernel(const float* __restrict__ x,
                                                 const float* __restrict__ g,
                                                 const float* __restrict__ b,
                                                 u16* __restrict__ out) {
  int row = blockIdx.x;
  int t = threadIdx.x;
  const float4* xr = (const float4*)(x + (size_t)row * 1024);
  float4 v = xr[t];
  float s = v.x + v.y + v.z + v.w;
  float s2 = v.x * v.x + v.y * v.y + v.z * v.z + v.w * v.w;
#pragma unroll
  for (int off = 1; off < 64; off <<= 1) {
    s += __shfl_xor(s, off);
    s2 += __shfl_xor(s2, off);
  }
  __shared__ float red[8];
  int wv = t >> 6;
  if ((t & 63) == 0) { red[wv] = s; red[4 + wv] = s2; }
  __syncthreads();
  s = red[0] + red[1] + red[2] + red[3];
  s2 = red[4] + red[5] + red[6] + red[7];
  float mu = s * (1.0f / 1024.0f);
  float var = s2 * (1.0f / 1024.0f) - mu * mu;
  float rstd = rsqrtf(var + 1e-5f);
  const float4 gv = ((const float4*)g)[t];
  const float4 bv = ((const float4*)b)[t];
  ushort4 o;
  o.x = f2bf((v.x - mu) * rstd * gv.x + bv.x);
  o.y = f2bf((v.y - mu) * rstd * gv.y + bv.y);
  o.z = f2bf((v.z - mu) * rstd * gv.z + bv.z);
  o.w = f2bf((v.w - mu) * rstd * gv.w + bv.w);
  ((ushort4*)out)[(size_t)row * 256 + t] = o;
}

// ---------------- GEMM: C[M,N=1024] = A[M,K=1024](bf16) @ W[N,K](bf16)^T + bias ----------------
// MODE 0: bf16 row-major out. MODE 1: fp32 out = res + gamma*(acc+bias).
// MODE 2: bf16 per-head transposed out: out[((b*16+h)*64+d)*Sk + s], Sk = 1<<sk_shift.
template <int MODE>
__global__ __launch_bounds__(256) void gemm_kernel(
    const u16* __restrict__ A, const u16* __restrict__ W,
    const float* __restrict__ bias,
    u16* __restrict__ outb, float* __restrict__ outf,
    const float* __restrict__ res, const float* __restrict__ gamma,
    int sk_shift) {
  const int K = 1024, N = 1024;
  int m0 = blockIdx.x * 128, n0 = blockIdx.y * 128;
  int t = threadIdx.x, lane = t & 63, wv = t >> 6;
  int wr = wv >> 1, wc = wv & 1;
  int lr = lane & 15, lk = (lane >> 4) * 8;
  __shared__ u16 As[128 * 32];
  __shared__ u16 Ws[128 * 32];
  f32x4 acc[4][4] = {};
  for (int kt = 0; kt < K / 32; ++kt) {
#pragma unroll
    for (int i = 0; i < 2; ++i) {
      int c = i * 256 + t;
      int row = c >> 2, k8 = (c & 3) << 3;
      const u16* ga = A + (size_t)(m0 + row) * K + kt * 32 + k8;
      const u16* gw = W + (size_t)(n0 + row) * K + kt * 32 + k8;
      __builtin_amdgcn_global_load_lds((const as1_void*)ga, (as3_void*)(As + c * 8), 16, 0, 0);
      __builtin_amdgcn_global_load_lds((const as1_void*)gw, (as3_void*)(Ws + c * 8), 16, 0, 0);
    }
    __syncthreads();
    bf16x8 af[4], wf[4];
#pragma unroll
    for (int m = 0; m < 4; ++m)
      af[m] = *(const bf16x8*)(As + (wr * 64 + m * 16 + lr) * 32 + lk);
#pragma unroll
    for (int n = 0; n < 4; ++n)
      wf[n] = *(const bf16x8*)(Ws + (wc * 64 + n * 16 + lr) * 32 + lk);
#pragma unroll
    for (int m = 0; m < 4; ++m)
#pragma unroll
      for (int n = 0; n < 4; ++n)
        acc[m][n] = __builtin_amdgcn_mfma_f32_16x16x32_bf16(af[m], wf[n], acc[m][n], 0, 0, 0);
    __syncthreads();
  }
  // epilogue: D layout col = lane&15, row = (lane>>4)*4 + r
  int rowb = m0 + wr * 64 + (lane >> 4) * 4;
#pragma unroll
  for (int m = 0; m < 4; ++m) {
#pragma unroll
    for (int n = 0; n < 4; ++n) {
      int col = n0 + wc * 64 + n * 16 + lr;
      float bcol = bias[col];
#pragma unroll
      for (int r = 0; r < 4; ++r) {
        int row = rowb + m * 16 + r;
        float val = acc[m][n][r] + bcol;
        if (MODE == 0) {
          outb[(size_t)row * N + col] = f2bf(val);
        } else if (MODE == 1) {
          size_t idx = (size_t)row * N + col;
          outf[idx] = res[idx] + gamma[col] * val;
        } else {
          int bb = row >> sk_shift;
          int ss = row & ((1 << sk_shift) - 1);
          int h = col >> 6, d = col & 63;
          outb[((((size_t)bb * 16 + h) * 64 + d) << sk_shift) + ss] = f2bf(val);
        }
      }
    }
  }
}

// ---------------- flash attention, head_dim=64, H=16 ----------------
// Q: [B*Sq, 1024] bf16 ; K: [B*Sk, 1024] bf16 ; Vt: [B*16, 64, Sk] bf16
// ctx out: [B*Sq, 1024] bf16. grid = (Sq/64, 16, B), 256 thr (4 waves x 16 q-rows).
__global__ __launch_bounds__(256) void attn_kernel(
    const u16* __restrict__ Q, const u16* __restrict__ Kmat,
    const u16* __restrict__ Vt, u16* __restrict__ ctx,
    int Sq, int Sk) {
  int q0 = blockIdx.x * 64;
  int h = blockIdx.y, b = blockIdx.z;
  int t = threadIdx.x, lane = t & 63, wv = t >> 6;
  int lr = lane & 15, lg = lane >> 4;
  const u16* Qb = Q + ((size_t)(b * Sq + q0 + wv * 16)) * 1024 + h * 64;
  bf16x8 qf0 = *(const bf16x8*)(Qb + (size_t)lr * 1024 + lg * 8);
  bf16x8 qf1 = *(const bf16x8*)(Qb + (size_t)lr * 1024 + 32 + lg * 8);
  const u16* Kb = Kmat + (size_t)b * Sk * 1024 + h * 64;
  const u16* Vb = Vt + ((size_t)(b * 16 + h)) * 64 * Sk;
  __shared__ u16 Pl[4][16 * 64];
  u16* pw = Pl[wv];
  float m_run[4] = {-1e30f, -1e30f, -1e30f, -1e30f};
  float l_run[4] = {0.f, 0.f, 0.f, 0.f};
  f32x4 accO[4] = {};
  for (int k0 = 0; k0 < Sk; k0 += 64) {
    f32x4 s[4] = {};
#pragma unroll
    for (int n = 0; n < 4; ++n) {
      const u16* kp = Kb + (size_t)(k0 + n * 16 + lr) * 1024;
      bf16x8 kf0 = *(const bf16x8*)(kp + lg * 8);
      bf16x8 kf1 = *(const bf16x8*)(kp + 32 + lg * 8);
      s[n] = __builtin_amdgcn_mfma_f32_16x16x32_bf16(qf0, kf0, s[n], 0, 0, 0);
      s[n] = __builtin_amdgcn_mfma_f32_16x16x32_bf16(qf1, kf1, s[n], 0, 0, 0);
    }
    float fac[4];
    float pr[4][4];
#pragma unroll
    for (int r = 0; r < 4; ++r) {
      float mx = fmaxf(fmaxf(s[0][r], s[1][r]), fmaxf(s[2][r], s[3][r]));
      mx = fmaxf(mx, __shfl_xor(mx, 1));
      mx = fmaxf(mx, __shfl_xor(mx, 2));
      mx = fmaxf(mx, __shfl_xor(mx, 4));
      mx = fmaxf(mx, __shfl_xor(mx, 8));
      float mnew = fmaxf(m_run[r], mx * 0.125f);
      float sum = 0.f;
#pragma unroll
      for (int n = 0; n < 4; ++n) {
        float p = __expf(s[n][r] * 0.125f - mnew);
        pr[n][r] = p;
        sum += p;
      }
      sum += __shfl_xor(sum, 1);
      sum += __shfl_xor(sum, 2);
      sum += __shfl_xor(sum, 4);
      sum += __shfl_xor(sum, 8);
      float f = __expf(m_run[r] - mnew);
      l_run[r] = l_run[r] * f + sum;
      m_run[r] = mnew;
      fac[r] = f;
    }
#pragma unroll
    for (int n = 0; n < 4; ++n)
#pragma unroll
      for (int r = 0; r < 4; ++r)
        accO[n][r] *= fac[r];
    // P (D-layout) -> LDS -> A-layout
#pragma unroll
    for (int n = 0; n < 4; ++n)
#pragma unroll
      for (int r = 0; r < 4; ++r)
        pw[(lg * 4 + r) * 64 + n * 16 + lr] = f2bf(pr[n][r]);
#pragma unroll
    for (int kk = 0; kk < 2; ++kk) {
      bf16x8 pf = *(const bf16x8*)(pw + lr * 64 + kk * 32 + lg * 8);
#pragma unroll
      for (int n = 0; n < 4; ++n) {
        bf16x8 vf = *(const bf16x8*)(Vb + (size_t)(n * 16 + lr) * Sk + k0 + kk * 32 + lg * 8);
        accO[n] = __builtin_amdgcn_mfma_f32_16x16x32_bf16(pf, vf, accO[n], 0, 0, 0);
      }
    }
  }
  u16* cb = ctx + ((size_t)(b * Sq + q0 + wv * 16)) * 1024 + h * 64;
#pragma unroll
  for (int n = 0; n < 4; ++n) {
#pragma unroll
    for (int r = 0; r < 4; ++r) {
      float o = accO[n][r] * (1.0f / l_run[r]);
      cb[(size_t)(lg * 4 + r) * 1024 + n * 16 + lr] = f2bf(o);
    }
  }
}

extern "C" void kernel_launch(void* const* d_in, const int* in_sizes, int n_in,
                              void* d_out, int out_size, void* d_ws, size_t ws_size,
                              hipStream_t stream) {
  const float* v = (const float*)d_in[0];
  const float* l = (const float*)d_in[1];
  const float* ln_v_g = (const float*)d_in[2];
  const float* ln_v_b = (const float*)d_in[3];
  const float* ln_l_g = (const float*)d_in[4];
  const float* ln_l_b = (const float*)d_in[5];
  const float* gamma_v = (const float*)d_in[6];
  const float* gamma_l = (const float*)d_in[7];
  // 0 Wq_v2l, 1 Wk_v2l, 2 Wv_v2l, 3 Wo_v2l, 4 Wq_l2v, 5 Wk_l2v, 6 Wv_l2v, 7 Wo_l2v
  const float* Wf[8];
  const float* Bf[8];
  for (int i = 0; i < 8; ++i) {
    Wf[i] = (const float*)d_in[8 + 2 * i];
    Bf[i] = (const float*)d_in[9 + 2 * i];
  }
  float* v_out = (float*)d_out;
  float* l_out = v_out + (size_t)16384 * 1024;

  char* p = (char*)d_ws;
  auto alloc = [&](size_t bytes) {
    char* r = p;
    p += (bytes + 255) & ~(size_t)255;
    return r;
  };
  u16* Wbf[8];
  for (int i = 0; i < 8; ++i) Wbf[i] = (u16*)alloc((size_t)1024 * 1024 * 2);
  u16* vn   = (u16*)alloc((size_t)16384 * 1024 * 2);  // LN(v) bf16
  u16* lnm  = (u16*)alloc((size_t)4096 * 1024 * 2);   // LN(l) bf16
  u16* bufA = (u16*)alloc((size_t)16384 * 1024 * 2);  // Q_v2l -> K_l2v
  u16* bufB = (u16*)alloc((size_t)4096 * 1024 * 2);   // K_v2l -> Q_l2v
  u16* bufC = (u16*)alloc((size_t)4096 * 1024 * 2);   // Vt_v2l -> ctx_l2v
  u16* bufD = (u16*)alloc((size_t)16384 * 1024 * 2);  // ctx_v2l -> Vt_l2v

  for (int i = 0; i < 8; ++i)
    cvt_kernel<<<1024, 256, 0, stream>>>((const float4*)Wf[i], (ushort4*)Wbf[i], 262144);
  ln_kernel<<<16384, 256, 0, stream>>>(v, ln_v_g, ln_v_b, vn);
  ln_kernel<<<4096, 256, 0, stream>>>(l, ln_l_g, ln_l_b, lnm);

  dim3 blk(256);
  // ---- v2l: q = v_norm, k/v = l_norm ----
  gemm_kernel<0><<<dim3(128, 8), blk, 0, stream>>>(vn, Wbf[0], Bf[0], bufA, nullptr, nullptr, nullptr, 0);
  gemm_kernel<0><<<dim3(32, 8), blk, 0, stream>>>(lnm, Wbf[1], Bf[1], bufB, nullptr, nullptr, nullptr, 0);
  gemm_kernel<2><<<dim3(32, 8), blk, 0, stream>>>(lnm, Wbf[2], Bf[2], bufC, nullptr, nullptr, nullptr, 9);
  attn_kernel<<<dim3(32, 16, 8), blk, 0, stream>>>(bufA, bufB, bufC, bufD, 2048, 512);
  gemm_kernel<1><<<dim3(128, 8), blk, 0, stream>>>(bufD, Wbf[3], Bf[3], nullptr, v_out, v, gamma_v, 0);
  // ---- l2v: q = l_norm, k/v = v_norm ----
  gemm_kernel<0><<<dim3(32, 8), blk, 0, stream>>>(lnm, Wbf[4], Bf[4], bufB, nullptr, nullptr, nullptr, 0);
  gemm_kernel<0><<<dim3(128, 8), blk, 0, stream>>>(vn, Wbf[5], Bf[5], bufA, nullptr, nullptr, nullptr, 0);
  gemm_kernel<2><<<dim3(128, 8), blk, 0, stream>>>(vn, Wbf[6], Bf[6], bufD, nullptr, nullptr, nullptr, 11);
  attn_kernel<<<dim3(8, 16, 8), blk, 0, stream>>>(bufB, bufA, bufD, bufC, 512, 2048);
  gemm_kernel<1><<<dim3(32, 8), blk, 0, stream>>>(bufC, Wbf[7], Bf[7], nullptr, l_out, l, gamma_l, 0);
}

// Round 2
// 600.367 us; speedup vs baseline: 1.7009x; 1.7009x over previous
//
#include <hip/hip_runtime.h>
#include <hip/hip_bf16.h>
#include <stdint.h>

typedef __bf16 bf16x8 __attribute__((ext_vector_type(8)));
typedef float f32x4 __attribute__((ext_vector_type(4)));
typedef unsigned short u16;

typedef __attribute__((address_space(1))) void as1_void;
typedef __attribute__((address_space(3))) void as3_void;

__device__ __forceinline__ u16 f2bf(float f) {
  uint32_t u = __float_as_uint(f);
  u += 0x7fffu + ((u >> 16) & 1u);
  return (u16)(u >> 16);
}

// ---------------- fp32 -> bf16 convert (weights) ----------------
__global__ __launch_bounds__(256) void cvt_kernel(const float4* __restrict__ in,
                                                  ushort4* __restrict__ out, int n4) {
  int i = blockIdx.x * 256 + threadIdx.x;
  if (i < n4) {
    float4 v = in[i];
    ushort4 o;
    o.x = f2bf(v.x); o.y = f2bf(v.y); o.z = f2bf(v.z); o.w = f2bf(v.w);
    out[i] = o;
  }
}

// ---------------- layernorm fp32 -> bf16, D=1024 ----------------
__global__ __launch_bounds__(256) void ln_kernel(const float* __restrict__ x,
                                                 const float* __restrict__ g,
                                                 const float* __restrict__ b,
                                                 u16* __restrict__ out) {
  int row = blockIdx.x;
  int t = threadIdx.x;
  const float4* xr = (const float4*)(x + (size_t)row * 1024);
  float4 v = xr[t];
  float s = v.x + v.y + v.z + v.w;
  float s2 = v.x * v.x + v.y * v.y + v.z * v.z + v.w * v.w;
#pragma unroll
  for (int off = 1; off < 64; off <<= 1) {
    s += __shfl_xor(s, off);
    s2 += __shfl_xor(s2, off);
  }
  __shared__ float red[8];
  int wv = t >> 6;
  if ((t & 63) == 0) { red[wv] = s; red[4 + wv] = s2; }
  __syncthreads();
  s = red[0] + red[1] + red[2] + red[3];
  s2 = red[4] + red[5] + red[6] + red[7];
  float mu = s * (1.0f / 1024.0f);
  float var = s2 * (1.0f / 1024.0f) - mu * mu;
  float rstd = rsqrtf(var + 1e-5f);
  const float4 gv = ((const float4*)g)[t];
  const float4 bv = ((const float4*)b)[t];
  ushort4 o;
  o.x = f2bf((v.x - mu) * rstd * gv.x + bv.x);
  o.y = f2bf((v.y - mu) * rstd * gv.y + bv.y);
  o.z = f2bf((v.z - mu) * rstd * gv.z + bv.z);
  o.w = f2bf((v.w - mu) * rstd * gv.w + bv.w);
  ((ushort4*)out)[(size_t)row * 256 + t] = o;
}

// ---------------- GEMM: C[M,N=1024] = A[M,K=1024](bf16) @ W[N,K](bf16)^T + bias ----------------
// MODE 0: bf16 row-major out. MODE 1: fp32 out = res + gamma*(acc+bias).
// MODE 2: bf16 per-head transposed out: out[((b*16+h)*64+d)*Sk + s], Sk = 1<<sk_shift.
template <int MODE>
__global__ __launch_bounds__(256) void gemm_kernel(
    const u16* __restrict__ A, const u16* __restrict__ W,
    const float* __restrict__ bias,
    u16* __restrict__ outb, float* __restrict__ outf,
    const float* __restrict__ res, const float* __restrict__ gamma,
    int sk_shift) {
  const int K = 1024, N = 1024;
  int m0 = blockIdx.x * 128, n0 = blockIdx.y * 128;
  int t = threadIdx.x, lane = t & 63, wv = t >> 6;
  int wr = wv >> 1, wc = wv & 1;
  int lr = lane & 15, lk = (lane >> 4) * 8;
  __shared__ u16 As[128 * 32];
  __shared__ u16 Ws[128 * 32];
  f32x4 acc[4][4] = {};
  for (int kt = 0; kt < K / 32; ++kt) {
#pragma unroll
    for (int i = 0; i < 2; ++i) {
      int c = i * 256 + t;
      int row = c >> 2, k8 = (c & 3) << 3;
      const u16* ga = A + (size_t)(m0 + row) * K + kt * 32 + k8;
      const u16* gw = W + (size_t)(n0 + row) * K + kt * 32 + k8;
      __builtin_amdgcn_global_load_lds((const as1_void*)ga, (as3_void*)(As + c * 8), 16, 0, 0);
      __builtin_amdgcn_global_load_lds((const as1_void*)gw, (as3_void*)(Ws + c * 8), 16, 0, 0);
    }
    __syncthreads();
    bf16x8 af[4], wf[4];
#pragma unroll
    for (int m = 0; m < 4; ++m)
      af[m] = *(const bf16x8*)(As + (wr * 64 + m * 16 + lr) * 32 + lk);
#pragma unroll
    for (int n = 0; n < 4; ++n)
      wf[n] = *(const bf16x8*)(Ws + (wc * 64 + n * 16 + lr) * 32 + lk);
#pragma unroll
    for (int m = 0; m < 4; ++m)
#pragma unroll
      for (int n = 0; n < 4; ++n)
        acc[m][n] = __builtin_amdgcn_mfma_f32_16x16x32_bf16(af[m], wf[n], acc[m][n], 0, 0, 0);
    __syncthreads();
  }
  int rowb = m0 + wr * 64 + (lane >> 4) * 4;
#pragma unroll
  for (int m = 0; m < 4; ++m) {
#pragma unroll
    for (int n = 0; n < 4; ++n) {
      int col = n0 + wc * 64 + n * 16 + lr;
      float bcol = bias[col];
#pragma unroll
      for (int r = 0; r < 4; ++r) {
        int row = rowb + m * 16 + r;
        float val = acc[m][n][r] + bcol;
        if (MODE == 0) {
          outb[(size_t)row * N + col] = f2bf(val);
        } else if (MODE == 1) {
          size_t idx = (size_t)row * N + col;
          outf[idx] = res[idx] + gamma[col] * val;
        } else {
          int bb = row >> sk_shift;
          int ss = row & ((1 << sk_shift) - 1);
          int h = col >> 6, d = col & 63;
          outb[((((size_t)bb * 16 + h) * 64 + d) << sk_shift) + ss] = f2bf(val);
        }
      }
    }
  }
}

// ---------------- flash attention, head_dim=64, H=16, B=8 ----------------
// Q: [B*Sq, 1024] bf16 ; K: [B*Sk, 1024] bf16 ; Vt: [B*16, 64, Sk] bf16
// ctx out: [B*Sq, 1024] bf16.
// 512 threads (8 waves x 16 q-rows = 128 q-rows/block). K/Vt tiles (64x64)
// LDS-staged (XOR-swizzled via pre-swizzled global source), double-buffered.
// 1-D grid, XCD-grouped: all q-tiles of one (b,h) land on one XCD.
__global__ __launch_bounds__(512) void attn_kernel(
    const u16* __restrict__ Q, const u16* __restrict__ Kmat,
    const u16* __restrict__ Vt, u16* __restrict__ ctx,
    int Sq, int Sk, int nq_shift) {
  int f = blockIdx.x;
  int xcd = f & 7, slot = f >> 3;
  int group = xcd * 16 + (slot >> nq_shift);  // 16 = (B*H)/8
  int qt = slot & ((1 << nq_shift) - 1);
  int b = group >> 4, h = group & 15;
  int t = threadIdx.x, lane = t & 63, wv = t >> 6;
  int lr = lane & 15, lg = lane >> 4;

  __shared__ u16 Ks[2][64 * 64];
  __shared__ u16 Vs[2][64 * 64];
  __shared__ u16 Pl[8][16 * 64];
  u16* pw = Pl[wv];

  const u16* Qb = Q + ((size_t)(b * Sq + qt * 128 + wv * 16)) * 1024 + h * 64;
  bf16x8 qf0 = *(const bf16x8*)(Qb + (size_t)lr * 1024 + lg * 8);
  bf16x8 qf1 = *(const bf16x8*)(Qb + (size_t)lr * 1024 + 32 + lg * 8);
  const u16* Kb = Kmat + (size_t)(b * Sk) * 1024 + h * 64;
  const u16* Vb = Vt + ((size_t)(b * 16 + h)) * 64 * Sk;

  // staging: thread t owns LDS 16B-block (row = t>>3, blk = t&7);
  // content is the swizzled block (blk ^ (row&7)) from global (rule #21:
  // linear LDS dest + inverse-swizzled per-lane global source).
  int trow = t >> 3, tblk = t & 7;
  int srcoff = ((tblk ^ (trow & 7)) * 8);
  const u16* gk = Kb + (size_t)trow * 1024 + srcoff;
  const u16* gv = Vb + (size_t)trow * Sk + srcoff;

  __builtin_amdgcn_global_load_lds((const as1_void*)gk, (as3_void*)(Ks[0] + t * 8), 16, 0, 0);
  __builtin_amdgcn_global_load_lds((const as1_void*)gv, (as3_void*)(Vs[0] + t * 8), 16, 0, 0);
  __syncthreads();

  float m_run[4] = {-1e30f, -1e30f, -1e30f, -1e30f};
  float l_run[4] = {0.f, 0.f, 0.f, 0.f};
  f32x4 accO[4] = {};
  int nt = Sk >> 6;
  for (int kt = 0; kt < nt; ++kt) {
    int cur = kt & 1;
    if (kt + 1 < nt) {  // issue next-tile stage; lands before next barrier
      const u16* gk2 = gk + (size_t)(kt + 1) * 64 * 1024;
      const u16* gv2 = gv + (size_t)(kt + 1) * 64;
      __builtin_amdgcn_global_load_lds((const as1_void*)gk2, (as3_void*)(Ks[cur ^ 1] + t * 8), 16, 0, 0);
      __builtin_amdgcn_global_load_lds((const as1_void*)gv2, (as3_void*)(Vs[cur ^ 1] + t * 8), 16, 0, 0);
    }
    // ---- QK^T ----
    f32x4 s[4] = {};
    __builtin_amdgcn_s_setprio(1);
#pragma unroll
    for (int n = 0; n < 4; ++n) {
      int row = n * 16 + lr;
      const u16* kp = Ks[cur] + row * 64;
      int sw = row & 7;
      bf16x8 kf0 = *(const bf16x8*)(kp + ((lg ^ sw) * 8));
      bf16x8 kf1 = *(const bf16x8*)(kp + (((4 + lg) ^ sw) * 8));
      s[n] = __builtin_amdgcn_mfma_f32_16x16x32_bf16(qf0, kf0, s[n], 0, 0, 0);
      s[n] = __builtin_amdgcn_mfma_f32_16x16x32_bf16(qf1, kf1, s[n], 0, 0, 0);
    }
    __builtin_amdgcn_s_setprio(0);
    // ---- online softmax ----
    float fac[4];
    float pr[4][4];
#pragma unroll
    for (int r = 0; r < 4; ++r) {
      float mx = fmaxf(fmaxf(s[0][r], s[1][r]), fmaxf(s[2][r], s[3][r]));
      mx = fmaxf(mx, __shfl_xor(mx, 1));
      mx = fmaxf(mx, __shfl_xor(mx, 2));
      mx = fmaxf(mx, __shfl_xor(mx, 4));
      mx = fmaxf(mx, __shfl_xor(mx, 8));
      float mnew = fmaxf(m_run[r], mx * 0.125f);
      float sum = 0.f;
#pragma unroll
      for (int n = 0; n < 4; ++n) {
        float p = __expf(s[n][r] * 0.125f - mnew);
        pr[n][r] = p;
        sum += p;
      }
      sum += __shfl_xor(sum, 1);
      sum += __shfl_xor(sum, 2);
      sum += __shfl_xor(sum, 4);
      sum += __shfl_xor(sum, 8);
      float ff = __expf(m_run[r] - mnew);
      l_run[r] = l_run[r] * ff + sum;
      m_run[r] = mnew;
      fac[r] = ff;
    }
#pragma unroll
    for (int n = 0; n < 4; ++n)
#pragma unroll
      for (int r = 0; r < 4; ++r)
        accO[n][r] *= fac[r];
    // ---- P (D-layout) -> LDS (swizzled) ----
#pragma unroll
    for (int n = 0; n < 4; ++n)
#pragma unroll
      for (int r = 0; r < 4; ++r) {
        int row2 = lg * 4 + r;
        int col = n * 16 + lr;
        int idx = row2 * 64 + (((((col >> 3) ^ (row2 & 7))) << 3) | (col & 7));
        pw[idx] = f2bf(pr[n][r]);
      }
    // ---- PV ----
    __builtin_amdgcn_s_setprio(1);
#pragma unroll
    for (int kk = 0; kk < 2; ++kk) {
      int pb = (kk * 4 + lg) ^ (lr & 7);
      bf16x8 pf = *(const bf16x8*)(pw + lr * 64 + pb * 8);
#pragma unroll
      for (int n = 0; n < 4; ++n) {
        int row = n * 16 + lr;
        int vb = (kk * 4 + lg) ^ (row & 7);
        bf16x8 vf = *(const bf16x8*)(Vs[cur] + row * 64 + vb * 8);
        accO[n] = __builtin_amdgcn_mfma_f32_16x16x32_bf16(pf, vf, accO[n], 0, 0, 0);
      }
    }
    __builtin_amdgcn_s_setprio(0);
    __syncthreads();  // drains staged loads (vmcnt) + guards buffer swap
  }
  u16* cb = ctx + ((size_t)(b * Sq + qt * 128 + wv * 16)) * 1024 + h * 64;
#pragma unroll
  for (int n = 0; n < 4; ++n) {
#pragma unroll
    for (int r = 0; r < 4; ++r) {
      float o = accO[n][r] * (1.0f / l_run[r]);
      cb[(size_t)(lg * 4 + r) * 1024 + n * 16 + lr] = f2bf(o);
    }
  }
}

extern "C" void kernel_launch(void* const* d_in, const int* in_sizes, int n_in,
                              void* d_out, int out_size, void* d_ws, size_t ws_size,
                              hipStream_t stream) {
  const float* v = (const float*)d_in[0];
  const float* l = (const float*)d_in[1];
  const float* ln_v_g = (const float*)d_in[2];
  const float* ln_v_b = (const float*)d_in[3];
  const float* ln_l_g = (const float*)d_in[4];
  const float* ln_l_b = (const float*)d_in[5];
  const float* gamma_v = (const float*)d_in[6];
  const float* gamma_l = (const float*)d_in[7];
  const float* Wf[8];
  const float* Bf[8];
  for (int i = 0; i < 8; ++i) {
    Wf[i] = (const float*)d_in[8 + 2 * i];
    Bf[i] = (const float*)d_in[9 + 2 * i];
  }
  float* v_out = (float*)d_out;
  float* l_out = v_out + (size_t)16384 * 1024;

  char* p = (char*)d_ws;
  auto alloc = [&](size_t bytes) {
    char* r = p;
    p += (bytes + 255) & ~(size_t)255;
    return r;
  };
  u16* Wbf[8];
  for (int i = 0; i < 8; ++i) Wbf[i] = (u16*)alloc((size_t)1024 * 1024 * 2);
  u16* vn   = (u16*)alloc((size_t)16384 * 1024 * 2);
  u16* lnm  = (u16*)alloc((size_t)4096 * 1024 * 2);
  u16* bufA = (u16*)alloc((size_t)16384 * 1024 * 2);
  u16* bufB = (u16*)alloc((size_t)4096 * 1024 * 2);
  u16* bufC = (u16*)alloc((size_t)4096 * 1024 * 2);
  u16* bufD = (u16*)alloc((size_t)16384 * 1024 * 2);

  for (int i = 0; i < 8; ++i)
    cvt_kernel<<<1024, 256, 0, stream>>>((const float4*)Wf[i], (ushort4*)Wbf[i], 262144);
  ln_kernel<<<16384, 256, 0, stream>>>(v, ln_v_g, ln_v_b, vn);
  ln_kernel<<<4096, 256, 0, stream>>>(l, ln_l_g, ln_l_b, lnm);

  dim3 blk(256);
  // ---- v2l: q = v_norm, k/v = l_norm ----
  gemm_kernel<0><<<dim3(128, 8), blk, 0, stream>>>(vn, Wbf[0], Bf[0], bufA, nullptr, nullptr, nullptr, 0);
  gemm_kernel<0><<<dim3(32, 8), blk, 0, stream>>>(lnm, Wbf[1], Bf[1], bufB, nullptr, nullptr, nullptr, 0);
  gemm_kernel<2><<<dim3(32, 8), blk, 0, stream>>>(lnm, Wbf[2], Bf[2], bufC, nullptr, nullptr, nullptr, 9);
  attn_kernel<<<dim3(2048), dim3(512), 0, stream>>>(bufA, bufB, bufC, bufD, 2048, 512, 4);
  gemm_kernel<1><<<dim3(128, 8), blk, 0, stream>>>(bufD, Wbf[3], Bf[3], nullptr, v_out, v, gamma_v, 0);
  // ---- l2v: q = l_norm, k/v = v_norm ----
  gemm_kernel<0><<<dim3(32, 8), blk, 0, stream>>>(lnm, Wbf[4], Bf[4], bufB, nullptr, nullptr, nullptr, 0);
  gemm_kernel<0><<<dim3(128, 8), blk, 0, stream>>>(vn, Wbf[5], Bf[5], bufA, nullptr, nullptr, nullptr, 0);
  gemm_kernel<2><<<dim3(128, 8), blk, 0, stream>>>(vn, Wbf[6], Bf[6], bufD, nullptr, nullptr, nullptr, 11);
  attn_kernel<<<dim3(512), dim3(512), 0, stream>>>(bufB, bufA, bufD, bufC, 512, 2048, 2);
  gemm_kernel<1><<<dim3(32, 8), blk, 0, stream>>>(bufC, Wbf[7], Bf[7], nullptr, l_out, l, gamma_l, 0);
}

// Round 3
// 519.925 us; speedup vs baseline: 1.9641x; 1.1547x over previous
//
#include <hip/hip_runtime.h>
#include <hip/hip_bf16.h>
#include <stdint.h>

typedef __bf16 bf16x8 __attribute__((ext_vector_type(8)));
typedef float f32x4 __attribute__((ext_vector_type(4)));
typedef unsigned short u16;

typedef __attribute__((address_space(1))) void as1_void;
typedef __attribute__((address_space(3))) void as3_void;

#define BAR() __builtin_amdgcn_s_barrier()
#define VMCNT(n) asm volatile("s_waitcnt vmcnt(" #n ")" ::: "memory")
#define LGKM0() asm volatile("s_waitcnt lgkmcnt(0)" ::: "memory")

__device__ __forceinline__ u16 f2bf(float f) {
  uint32_t u = __float_as_uint(f);
  u += 0x7fffu + ((u >> 16) & 1u);
  return (u16)(u >> 16);
}

// ---------------- fp32 -> bf16 convert (all 8 weights, one dispatch) ----------------
__global__ __launch_bounds__(256) void cvt8_kernel(
    const float4* s0, const float4* s1, const float4* s2, const float4* s3,
    const float4* s4, const float4* s5, const float4* s6, const float4* s7,
    ushort4* d0, ushort4* d1, ushort4* d2, ushort4* d3,
    ushort4* d4, ushort4* d5, ushort4* d6, ushort4* d7) {
  const float4* s; ushort4* d;
  switch (blockIdx.y) {
    case 0: s = s0; d = d0; break;
    case 1: s = s1; d = d1; break;
    case 2: s = s2; d = d2; break;
    case 3: s = s3; d = d3; break;
    case 4: s = s4; d = d4; break;
    case 5: s = s5; d = d5; break;
    case 6: s = s6; d = d6; break;
    default: s = s7; d = d7; break;
  }
  int i = blockIdx.x * 256 + threadIdx.x;
  float4 v = s[i];
  ushort4 o;
  o.x = f2bf(v.x); o.y = f2bf(v.y); o.z = f2bf(v.z); o.w = f2bf(v.w);
  d[i] = o;
}

// ---------------- layernorm fp32 -> bf16, D=1024 ----------------
__global__ __launch_bounds__(256) void ln_kernel(const float* __restrict__ x,
                                                 const float* __restrict__ g,
                                                 const float* __restrict__ b,
                                                 u16* __restrict__ out) {
  int row = blockIdx.x;
  int t = threadIdx.x;
  const float4* xr = (const float4*)(x + (size_t)row * 1024);
  float4 v = xr[t];
  float s = v.x + v.y + v.z + v.w;
  float s2 = v.x * v.x + v.y * v.y + v.z * v.z + v.w * v.w;
#pragma unroll
  for (int off = 1; off < 64; off <<= 1) {
    s += __shfl_xor(s, off);
    s2 += __shfl_xor(s2, off);
  }
  __shared__ float red[8];
  int wv = t >> 6;
  if ((t & 63) == 0) { red[wv] = s; red[4 + wv] = s2; }
  __syncthreads();
  s = red[0] + red[1] + red[2] + red[3];
  s2 = red[4] + red[5] + red[6] + red[7];
  float mu = s * (1.0f / 1024.0f);
  float var = s2 * (1.0f / 1024.0f) - mu * mu;
  float rstd = rsqrtf(var + 1e-5f);
  const float4 gv = ((const float4*)g)[t];
  const float4 bv = ((const float4*)b)[t];
  ushort4 o;
  o.x = f2bf((v.x - mu) * rstd * gv.x + bv.x);
  o.y = f2bf((v.y - mu) * rstd * gv.y + bv.y);
  o.z = f2bf((v.z - mu) * rstd * gv.z + bv.z);
  o.w = f2bf((v.w - mu) * rstd * gv.w + bv.w);
  ((ushort4*)out)[(size_t)row * 256 + t] = o;
}

// ================= 128x128 GEMM (m97 structure) — small-M GEMMs =================
// C[M,1024] = A[M,1024] @ W[1024,1024]^T + bias. Modes as below.
template <int MODE>
__global__ __launch_bounds__(256) void gemm_kernel(
    const u16* __restrict__ A, const u16* __restrict__ W,
    const float* __restrict__ bias,
    u16* __restrict__ outb, float* __restrict__ outf,
    const float* __restrict__ res, const float* __restrict__ gamma,
    int sk_shift) {
  const int K = 1024, N = 1024;
  int m0 = blockIdx.x * 128, n0 = blockIdx.y * 128;
  int t = threadIdx.x, lane = t & 63, wv = t >> 6;
  int wr = wv >> 1, wc = wv & 1;
  int lr = lane & 15, lk = (lane >> 4) * 8;
  __shared__ u16 As[128 * 32];
  __shared__ u16 Ws[128 * 32];
  f32x4 acc[4][4] = {};
  for (int kt = 0; kt < K / 32; ++kt) {
#pragma unroll
    for (int i = 0; i < 2; ++i) {
      int c = i * 256 + t;
      int row = c >> 2, k8 = (c & 3) << 3;
      const u16* ga = A + (size_t)(m0 + row) * K + kt * 32 + k8;
      const u16* gw = W + (size_t)(n0 + row) * K + kt * 32 + k8;
      __builtin_amdgcn_global_load_lds((const as1_void*)ga, (as3_void*)(As + c * 8), 16, 0, 0);
      __builtin_amdgcn_global_load_lds((const as1_void*)gw, (as3_void*)(Ws + c * 8), 16, 0, 0);
    }
    __syncthreads();
    bf16x8 af[4], wf[4];
#pragma unroll
    for (int m = 0; m < 4; ++m)
      af[m] = *(const bf16x8*)(As + (wr * 64 + m * 16 + lr) * 32 + lk);
#pragma unroll
    for (int n = 0; n < 4; ++n)
      wf[n] = *(const bf16x8*)(Ws + (wc * 64 + n * 16 + lr) * 32 + lk);
#pragma unroll
    for (int m = 0; m < 4; ++m)
#pragma unroll
      for (int n = 0; n < 4; ++n)
        acc[m][n] = __builtin_amdgcn_mfma_f32_16x16x32_bf16(af[m], wf[n], acc[m][n], 0, 0, 0);
    __syncthreads();
  }
  int rowb = m0 + wr * 64 + (lane >> 4) * 4;
#pragma unroll
  for (int m = 0; m < 4; ++m) {
#pragma unroll
    for (int n = 0; n < 4; ++n) {
      int col = n0 + wc * 64 + n * 16 + lr;
      float bcol = bias[col];
#pragma unroll
      for (int r = 0; r < 4; ++r) {
        int row = rowb + m * 16 + r;
        float val = acc[m][n][r] + bcol;
        if (MODE == 0) {
          outb[(size_t)row * N + col] = f2bf(val);
        } else if (MODE == 1) {
          size_t idx = (size_t)row * N + col;
          outf[idx] = res[idx] + gamma[col] * val;
        } else {
          int bb = row >> sk_shift;
          int ss = row & ((1 << sk_shift) - 1);
          int h = col >> 6, d = col & 63;
          outb[((((size_t)bb * 16 + h) * 64 + d) << sk_shift) + ss] = f2bf(val);
        }
      }
    }
  }
}

// ================= 256x256 8-phase GEMM (T2+T3+T4+T5) — big-M GEMMs =================
// BM=BN=256, BK=64, 8 waves (wm 0..1, wn 0..3), per-wave C = 128x64.
// LDS: 2 bufs x one K-tile each: A[256][64] + B[256][64] bf16, XOR block-swizzled
// (blk ^ (row&7)) via pre-swizzled global source. vmcnt(8) at phases 4/8.
template <int MODE>
__global__ __launch_bounds__(512, 2) void gemm256_kernel(
    const u16* __restrict__ A, const u16* __restrict__ W,
    const float* __restrict__ bias,
    u16* __restrict__ outb, float* __restrict__ outf,
    const float* __restrict__ res, const float* __restrict__ gamma,
    int mtiles, int sk_shift) {
  const int K = 1024, N = 1024;
  // bijective XCD swizzle: nwg = mtiles*4 (divisible by 8 for our shapes)
  int nwg = mtiles * 4;
  int cpx = nwg >> 3;
  int bid = blockIdx.x;
  int swz = (bid & 7) * cpx + (bid >> 3);
  int mt = swz >> 2, nt = swz & 3;
  int m0 = mt * 256, n0 = nt * 256;

  int t = threadIdx.x, lane = t & 63, wv = t >> 6;
  int wm = wv >> 2, wn = wv & 3;
  int lr = lane & 15, lg = lane >> 4;
  int sa0 = ((lg) ^ (lr & 7)) * 8;
  int sa1 = ((4 + lg) ^ (lr & 7)) * 8;

  __shared__ u16 AB[2][2][256 * 64];  // [buf][0=A,1=B]
  u16* ldsA0 = &AB[0][0][0];
  u16* ldsB0 = &AB[0][1][0];
  u16* ldsA1 = &AB[1][0][0];
  u16* ldsB1 = &AB[1][1][0];

  // staging geometry: thread t owns LDS blocks t and t+512 of each half-tile
  int r0 = t >> 3, c0 = t & 7;
  int cs0 = c0 ^ (r0 & 7);
  const u16* gA0 = A + (size_t)(m0 + r0) * K + cs0 * 8;
  const u16* gA1 = gA0 + (size_t)64 * K;
  const u16* gB0 = W + (size_t)(n0 + r0) * K + cs0 * 8;
  const u16* gB1 = gB0 + (size_t)64 * K;

  auto STG = [&](u16* ldsbase, const u16* g0, const u16* g1, int half, int kt) {
    __builtin_amdgcn_global_load_lds(
        (const as1_void*)(g0 + (size_t)half * 128 * K + kt * 64),
        (as3_void*)(ldsbase + (half * 128 + r0) * 64 + c0 * 8), 16, 0, 0);
    __builtin_amdgcn_global_load_lds(
        (const as1_void*)(g1 + (size_t)half * 128 * K + kt * 64),
        (as3_void*)(ldsbase + (half * 128 + r0 + 64) * 64 + c0 * 8), 16, 0, 0);
  };

  f32x4 acc[8][4] = {};
  bf16x8 aX[4][2], bX[2][2], bY[2][2];

  auto LD_A = [&](const u16* base, int mo) {
#pragma unroll
    for (int m = 0; m < 4; ++m) {
      const u16* rp = base + (wm * 128 + (mo + m) * 16 + lr) * 64;
      aX[m][0] = *(const bf16x8*)(rp + sa0);
      aX[m][1] = *(const bf16x8*)(rp + sa1);
    }
  };
  auto LD_B = [&](bf16x8 (&dst)[2][2], const u16* base, int no) {
#pragma unroll
    for (int n = 0; n < 2; ++n) {
      const u16* rp = base + (wn * 64 + (no + n) * 16 + lr) * 64;
      dst[n][0] = *(const bf16x8*)(rp + sa0);
      dst[n][1] = *(const bf16x8*)(rp + sa1);
    }
  };
  auto QD = [&](bf16x8 (&bf)[2][2], int mo, int no) {
#pragma unroll
    for (int m = 0; m < 4; ++m)
#pragma unroll
      for (int n = 0; n < 2; ++n) {
        acc[mo + m][no + n] = __builtin_amdgcn_mfma_f32_16x16x32_bf16(
            aX[m][0], bf[n][0], acc[mo + m][no + n], 0, 0, 0);
        acc[mo + m][no + n] = __builtin_amdgcn_mfma_f32_16x16x32_bf16(
            aX[m][1], bf[n][1], acc[mo + m][no + n], 0, 0, 0);
      }
  };

  // prologue: kt0 -> buf0, kt1 -> buf1
  STG(ldsA0, gA0, gA1, 0, 0); STG(ldsA0, gA0, gA1, 1, 0);
  STG(ldsB0, gB0, gB1, 0, 0); STG(ldsB0, gB0, gB1, 1, 0);
  STG(ldsA1, gA0, gA1, 0, 1); STG(ldsA1, gA0, gA1, 1, 1);
  STG(ldsB1, gB0, gB1, 0, 1); STG(ldsB1, gB0, gB1, 1, 1);
  VMCNT(8);  // buf0's 8 loads retired; buf1 still in flight
  BAR();

  const int NIT = K / 128;  // 8
#pragma unroll 1
  for (int it = 0; it < NIT; ++it) {
    bool st = (it + 1 < NIT);
    int ktA = 2 * it;
    // ---- K-tile A (buf0) ----
    // P1
    LD_A(ldsA0, 0); LD_B(bX, ldsB0, 0);
    BAR(); LGKM0();
    __builtin_amdgcn_s_setprio(1); QD(bX, 0, 0); __builtin_amdgcn_s_setprio(0);
    BAR();
    // P2
    LD_B(bY, ldsB0, 2);
    BAR(); LGKM0();
    __builtin_amdgcn_s_setprio(1); QD(bY, 0, 2); __builtin_amdgcn_s_setprio(0);
    BAR();
    // P3 (B-region reads are done -> stage B halves of ktA+2 into buf0)
    LD_A(ldsA0, 4);
    if (st) { STG(ldsB0, gB0, gB1, 0, ktA + 2); STG(ldsB0, gB0, gB1, 1, ktA + 2); }
    BAR(); LGKM0();
    __builtin_amdgcn_s_setprio(1); QD(bY, 4, 2); __builtin_amdgcn_s_setprio(0);
    BAR();
    // P4 (A-region reads done -> stage A halves; counted vmcnt)
    if (st) { STG(ldsA0, gA0, gA1, 0, ktA + 2); STG(ldsA0, gA0, gA1, 1, ktA + 2); }
    if (st) { VMCNT(8); } else { VMCNT(0); }
    BAR();
    __builtin_amdgcn_s_setprio(1); QD(bX, 4, 0); __builtin_amdgcn_s_setprio(0);
    BAR();
    // ---- K-tile B (buf1) ----
    // P5
    LD_A(ldsA1, 0); LD_B(bX, ldsB1, 0);
    BAR(); LGKM0();
    __builtin_amdgcn_s_setprio(1); QD(bX, 0, 0); __builtin_amdgcn_s_setprio(0);
    BAR();
    // P6
    LD_B(bY, ldsB1, 2);
    BAR(); LGKM0();
    __builtin_amdgcn_s_setprio(1); QD(bY, 0, 2); __builtin_amdgcn_s_setprio(0);
    BAR();
    // P7
    LD_A(ldsA1, 4);
    if (st) { STG(ldsB1, gB0, gB1, 0, ktA + 3); STG(ldsB1, gB0, gB1, 1, ktA + 3); }
    BAR(); LGKM0();
    __builtin_amdgcn_s_setprio(1); QD(bY, 4, 2); __builtin_amdgcn_s_setprio(0);
    BAR();
    // P8
    if (st) { STG(ldsA1, gA0, gA1, 0, ktA + 3); STG(ldsA1, gA0, gA1, 1, ktA + 3); }
    if (st) { VMCNT(8); }
    BAR();
    __builtin_amdgcn_s_setprio(1); QD(bX, 4, 0); __builtin_amdgcn_s_setprio(0);
    BAR();
  }

  // epilogue
  int rowb = m0 + wm * 128 + lg * 4;
#pragma unroll
  for (int mi = 0; mi < 8; ++mi) {
#pragma unroll
    for (int n = 0; n < 4; ++n) {
      int col = n0 + wn * 64 + n * 16 + lr;
      float bcol = bias[col];
#pragma unroll
      for (int r = 0; r < 4; ++r) {
        int row = rowb + mi * 16 + r;
        float val = acc[mi][n][r] + bcol;
        if (MODE == 0) {
          outb[(size_t)row * N + col] = f2bf(val);
        } else if (MODE == 1) {
          size_t idx = (size_t)row * N + col;
          outf[idx] = res[idx] + gamma[col] * val;
        } else {
          int bb = row >> sk_shift;
          int ss = row & ((1 << sk_shift) - 1);
          int h = col >> 6, d = col & 63;
          outb[((((size_t)bb * 16 + h) * 64 + d) << sk_shift) + ss] = f2bf(val);
        }
      }
    }
  }
}

// ---------------- flash attention, head_dim=64, H=16, B=8 ----------------
__global__ __launch_bounds__(512) void attn_kernel(
    const u16* __restrict__ Q, const u16* __restrict__ Kmat,
    const u16* __restrict__ Vt, u16* __restrict__ ctx,
    int Sq, int Sk, int nq_shift) {
  int f = blockIdx.x;
  int xcd = f & 7, slot = f >> 3;
  int group = xcd * 16 + (slot >> nq_shift);
  int qt = slot & ((1 << nq_shift) - 1);
  int b = group >> 4, h = group & 15;
  int t = threadIdx.x, lane = t & 63, wv = t >> 6;
  int lr = lane & 15, lg = lane >> 4;

  __shared__ u16 Ks[2][64 * 64];
  __shared__ u16 Vs[2][64 * 64];
  __shared__ u16 Pl[8][16 * 64];
  u16* pw = Pl[wv];

  const u16* Qb = Q + ((size_t)(b * Sq + qt * 128 + wv * 16)) * 1024 + h * 64;
  bf16x8 qf0 = *(const bf16x8*)(Qb + (size_t)lr * 1024 + lg * 8);
  bf16x8 qf1 = *(const bf16x8*)(Qb + (size_t)lr * 1024 + 32 + lg * 8);
  const u16* Kb = Kmat + (size_t)(b * Sk) * 1024 + h * 64;
  const u16* Vb = Vt + ((size_t)(b * 16 + h)) * 64 * Sk;

  int trow = t >> 3, tblk = t & 7;
  int srcoff = ((tblk ^ (trow & 7)) * 8);
  const u16* gk = Kb + (size_t)trow * 1024 + srcoff;
  const u16* gv = Vb + (size_t)trow * Sk + srcoff;

  __builtin_amdgcn_global_load_lds((const as1_void*)gk, (as3_void*)(Ks[0] + t * 8), 16, 0, 0);
  __builtin_amdgcn_global_load_lds((const as1_void*)gv, (as3_void*)(Vs[0] + t * 8), 16, 0, 0);
  __syncthreads();

  float m_run[4] = {-1e30f, -1e30f, -1e30f, -1e30f};
  float l_run[4] = {0.f, 0.f, 0.f, 0.f};
  f32x4 accO[4] = {};
  int nt = Sk >> 6;
  for (int kt = 0; kt < nt; ++kt) {
    int cur = kt & 1;
    if (kt + 1 < nt) {
      const u16* gk2 = gk + (size_t)(kt + 1) * 64 * 1024;
      const u16* gv2 = gv + (size_t)(kt + 1) * 64;
      __builtin_amdgcn_global_load_lds((const as1_void*)gk2, (as3_void*)(Ks[cur ^ 1] + t * 8), 16, 0, 0);
      __builtin_amdgcn_global_load_lds((const as1_void*)gv2, (as3_void*)(Vs[cur ^ 1] + t * 8), 16, 0, 0);
    }
    f32x4 s[4] = {};
    __builtin_amdgcn_s_setprio(1);
#pragma unroll
    for (int n = 0; n < 4; ++n) {
      int row = n * 16 + lr;
      const u16* kp = Ks[cur] + row * 64;
      int sw = row & 7;
      bf16x8 kf0 = *(const bf16x8*)(kp + ((lg ^ sw) * 8));
      bf16x8 kf1 = *(const bf16x8*)(kp + (((4 + lg) ^ sw) * 8));
      s[n] = __builtin_amdgcn_mfma_f32_16x16x32_bf16(qf0, kf0, s[n], 0, 0, 0);
      s[n] = __builtin_amdgcn_mfma_f32_16x16x32_bf16(qf1, kf1, s[n], 0, 0, 0);
    }
    __builtin_amdgcn_s_setprio(0);
    float fac[4];
    float pr[4][4];
#pragma unroll
    for (int r = 0; r < 4; ++r) {
      float mx = fmaxf(fmaxf(s[0][r], s[1][r]), fmaxf(s[2][r], s[3][r]));
      mx = fmaxf(mx, __shfl_xor(mx, 1));
      mx = fmaxf(mx, __shfl_xor(mx, 2));
      mx = fmaxf(mx, __shfl_xor(mx, 4));
      mx = fmaxf(mx, __shfl_xor(mx, 8));
      float mnew = fmaxf(m_run[r], mx * 0.125f);
      float sum = 0.f;
#pragma unroll
      for (int n = 0; n < 4; ++n) {
        float p = __expf(s[n][r] * 0.125f - mnew);
        pr[n][r] = p;
        sum += p;
      }
      sum += __shfl_xor(sum, 1);
      sum += __shfl_xor(sum, 2);
      sum += __shfl_xor(sum, 4);
      sum += __shfl_xor(sum, 8);
      float ff = __expf(m_run[r] - mnew);
      l_run[r] = l_run[r] * ff + sum;
      m_run[r] = mnew;
      fac[r] = ff;
    }
#pragma unroll
    for (int n = 0; n < 4; ++n)
#pragma unroll
      for (int r = 0; r < 4; ++r)
        accO[n][r] *= fac[r];
#pragma unroll
    for (int n = 0; n < 4; ++n)
#pragma unroll
      for (int r = 0; r < 4; ++r) {
        int row2 = lg * 4 + r;
        int col = n * 16 + lr;
        int idx = row2 * 64 + (((((col >> 3) ^ (row2 & 7))) << 3) | (col & 7));
        pw[idx] = f2bf(pr[n][r]);
      }
    __builtin_amdgcn_s_setprio(1);
#pragma unroll
    for (int kk = 0; kk < 2; ++kk) {
      int pb = (kk * 4 + lg) ^ (lr & 7);
      bf16x8 pf = *(const bf16x8*)(pw + lr * 64 + pb * 8);
#pragma unroll
      for (int n = 0; n < 4; ++n) {
        int row = n * 16 + lr;
        int vb = (kk * 4 + lg) ^ (row & 7);
        bf16x8 vf = *(const bf16x8*)(Vs[cur] + row * 64 + vb * 8);
        accO[n] = __builtin_amdgcn_mfma_f32_16x16x32_bf16(pf, vf, accO[n], 0, 0, 0);
      }
    }
    __builtin_amdgcn_s_setprio(0);
    __syncthreads();
  }
  u16* cb = ctx + ((size_t)(b * Sq + qt * 128 + wv * 16)) * 1024 + h * 64;
#pragma unroll
  for (int n = 0; n < 4; ++n) {
#pragma unroll
    for (int r = 0; r < 4; ++r) {
      float o = accO[n][r] * (1.0f / l_run[r]);
      cb[(size_t)(lg * 4 + r) * 1024 + n * 16 + lr] = f2bf(o);
    }
  }
}

extern "C" void kernel_launch(void* const* d_in, const int* in_sizes, int n_in,
                              void* d_out, int out_size, void* d_ws, size_t ws_size,
                              hipStream_t stream) {
  const float* v = (const float*)d_in[0];
  const float* l = (const float*)d_in[1];
  const float* ln_v_g = (const float*)d_in[2];
  const float* ln_v_b = (const float*)d_in[3];
  const float* ln_l_g = (const float*)d_in[4];
  const float* ln_l_b = (const float*)d_in[5];
  const float* gamma_v = (const float*)d_in[6];
  const float* gamma_l = (const float*)d_in[7];
  const float* Wf[8];
  const float* Bf[8];
  for (int i = 0; i < 8; ++i) {
    Wf[i] = (const float*)d_in[8 + 2 * i];
    Bf[i] = (const float*)d_in[9 + 2 * i];
  }
  float* v_out = (float*)d_out;
  float* l_out = v_out + (size_t)16384 * 1024;

  char* p = (char*)d_ws;
  auto alloc = [&](size_t bytes) {
    char* r = p;
    p += (bytes + 255) & ~(size_t)255;
    return r;
  };
  u16* Wbf[8];
  for (int i = 0; i < 8; ++i) Wbf[i] = (u16*)alloc((size_t)1024 * 1024 * 2);
  u16* vn   = (u16*)alloc((size_t)16384 * 1024 * 2);
  u16* lnm  = (u16*)alloc((size_t)4096 * 1024 * 2);
  u16* bufA = (u16*)alloc((size_t)16384 * 1024 * 2);
  u16* bufB = (u16*)alloc((size_t)4096 * 1024 * 2);
  u16* bufC = (u16*)alloc((size_t)4096 * 1024 * 2);
  u16* bufD = (u16*)alloc((size_t)16384 * 1024 * 2);

  cvt8_kernel<<<dim3(1024, 8), 256, 0, stream>>>(
      (const float4*)Wf[0], (const float4*)Wf[1], (const float4*)Wf[2], (const float4*)Wf[3],
      (const float4*)Wf[4], (const float4*)Wf[5], (const float4*)Wf[6], (const float4*)Wf[7],
      (ushort4*)Wbf[0], (ushort4*)Wbf[1], (ushort4*)Wbf[2], (ushort4*)Wbf[3],
      (ushort4*)Wbf[4], (ushort4*)Wbf[5], (ushort4*)Wbf[6], (ushort4*)Wbf[7]);
  ln_kernel<<<16384, 256, 0, stream>>>(v, ln_v_g, ln_v_b, vn);
  ln_kernel<<<4096, 256, 0, stream>>>(l, ln_l_g, ln_l_b, lnm);

  dim3 blk(256);
  dim3 blk512(512);
  // ---- v2l: q = v_norm, k/v = l_norm ----
  gemm256_kernel<0><<<dim3(256), blk512, 0, stream>>>(vn, Wbf[0], Bf[0], bufA, nullptr, nullptr, nullptr, 64, 0);
  gemm_kernel<0><<<dim3(32, 8), blk, 0, stream>>>(lnm, Wbf[1], Bf[1], bufB, nullptr, nullptr, nullptr, 0);
  gemm_kernel<2><<<dim3(32, 8), blk, 0, stream>>>(lnm, Wbf[2], Bf[2], bufC, nullptr, nullptr, nullptr, 9);
  attn_kernel<<<dim3(2048), blk512, 0, stream>>>(bufA, bufB, bufC, bufD, 2048, 512, 4);
  gemm256_kernel<1><<<dim3(256), blk512, 0, stream>>>(bufD, Wbf[3], Bf[3], nullptr, v_out, v, gamma_v, 64, 0);
  // ---- l2v: q = l_norm, k/v = v_norm ----
  gemm_kernel<0><<<dim3(32, 8), blk, 0, stream>>>(lnm, Wbf[4], Bf[4], bufB, nullptr, nullptr, nullptr, 0);
  gemm256_kernel<0><<<dim3(256), blk512, 0, stream>>>(vn, Wbf[5], Bf[5], bufA, nullptr, nullptr, nullptr, 64, 0);
  gemm256_kernel<2><<<dim3(256), blk512, 0, stream>>>(vn, Wbf[6], Bf[6], bufD, nullptr, nullptr, nullptr, 64, 11);
  attn_kernel<<<dim3(512), blk512, 0, stream>>>(bufB, bufA, bufD, bufC, 512, 2048, 2);
  gemm_kernel<1><<<dim3(32, 8), blk, 0, stream>>>(bufC, Wbf[7], Bf[7], nullptr, l_out, l, gamma_l, 0);
}